// Round 8
// baseline (150.311 us; speedup 1.0000x reference)
//
#include <hip/hip_runtime.h>

#define TT 512
#define BB 512
#define NN 64
#define LN2F 0.69314718055994530942f
#define SCH 64           // chunk length; 8 chunks cover t = 1..511
#define EXACT_THRESH 32  // boundary chunks shorter than this are replayed exactly

typedef _Float16 half8_t __attribute__((ext_vector_type(8)));
typedef float    f32x4   __attribute__((ext_vector_type(4)));

union AFrag { int u[4]; half8_t h; };

__device__ __forceinline__ float wave_max(float v) {
    #pragma unroll
    for (int off = 32; off > 0; off >>= 1)
        v = fmaxf(v, __shfl_xor(v, off, 64));
    return v;
}

__device__ __forceinline__ float wave_sum(float v) {
    #pragma unroll
    for (int off = 32; off > 0; off >>= 1)
        v += __shfl_xor(v, off, 64);
    return v;
}

__device__ __forceinline__ int wave_sum_i(int v) {
    #pragma unroll
    for (int off = 32; off > 0; off >>= 1)
        v += __shfl_xor(v, off, 64);
    return v;
}

// Zero the scalar output (harness poisons d_out with 0xAA before every launch).
__global__ void zero_kernel(float* __restrict__ out) {
    if (threadIdx.x == 0 && blockIdx.x == 0) out[0] = 0.0f;
}

// r20 = r19 (rank-1 chunking on 16-column MFMAs, verified) with the memory
// latency actually covered:
//  - main-loop register prefetch depth 2 -> 4 (16x f32x4 buffers): the
//    per-step scattered 16-row emit loads get a >=4-step lead, covering
//    L3/HBM latency (r19's 2-step lead left ~600-900 cyc/step of vmcnt
//    stall: VALUBusy 20%, MfmaUtil 5%, HBM 12% -- all idle).
//  - exact-replay loop gets a 1-row software pipeline (was fully exposed).
// All math (sigma feedback, delayed power-of-2 normalization, rank-1
// combine, boundary replay, LSE, gold) is r19-verbatim.
__global__ __launch_bounds__(192) void crf_fwd_kernel(
    const float* __restrict__ emit,
    const float* __restrict__ trans,
    const float* __restrict__ strans,
    const float* __restrict__ etrans,
    const int*   __restrict__ target,
    const void*  __restrict__ maskp,
    float* __restrict__ out)
{
    const int b   = blockIdx.x;
    const int tid = threadIdx.x;
    const int k   = tid & 63;
    const int wv  = tid >> 6;   // 0 = fwd chains, 1 = bwd chains, 2 = gold

    __shared__ float FL[8][NN];   // scaled F_c (state-indexed)
    __shared__ float RL[8][NN];   // scaled R_c
    __shared__ float xbuf[NN];
    __shared__ int   esF[8], esB[8];

    const int*           mi32 = (const int*)maskp;
    const unsigned char* mi8  = (const unsigned char*)maskp;
    // mask[0,:] is all-true (lengths >= 1): byte encoding -> word0 == 0x01010101.
    const bool bytemode = (mi32[0] == 0x01010101);

    // len[b] = sum_t mask[t,b] (monotone mask)
    int cnt = 0;
    #pragma unroll
    for (int i = 0; i < TT / 64; ++i) {
        const size_t tb = (size_t)(i * 64 + k) * BB + b;
        cnt += bytemode ? (mi8[tb] != 0) : (mi32[tb] != 0);
    }
    const int len = wave_sum_i(cnt);   // wave-uniform

    const int q    = k >> 4;
    const int m15  = k & 15;
    const int base = 8 * (m15 >> 2) + 2 * (m15 & 3);   // sigma(g,m)=32*(g>>1)+(g&1)+base

    const int  Bc    = (len >= 2) ? ((len - 2) / SCH) : 0;   // boundary chunk id (0..7)
    const int  sB    = len - (1 + SCH * Bc);                 // its step count (0..64)
    const bool exact = (Bc >= 1) && (sB < EXACT_THRESH);

    const f32x4 zero4 = {0.f, 0.f, 0.f, 0.f};
    float m0loc = 0.f;

    // Persist F-wave registers needed after the barrier (Af reused in replay).
    half8_t Af[4][2];
    float uLo[8], uHi[8];

    if (wv <= 1) {
        const bool fwd = (wv == 0);
        const int cF  = m15 & 7;                 // column's chunk (8..15 duplicate)
        const int t0  = 1 + SCH * cF;
        const int nst = min(max(len - t0, 0), SCH);
        const int tLq = t0 + nst - 1;            // bwd starts here, descending

        // A-fragments: F: A[m][kk]=0.25exp(trans[kk][sigma(g,m)]) (r16-verbatim);
        //              B: A[m][kk]=0.25exp(trans[sigma(g,m)][kk]) (transposed).
        #pragma unroll
        for (int g = 0; g < 4; ++g) {
            const int nsg = 32 * (g >> 1) + (g & 1) + base;
            #pragma unroll
            for (int kh = 0; kh < 2; ++kh) {
                AFrag af;
                #pragma unroll
                for (int jp = 0; jp < 4; ++jp) {
                    const int krow = 32 * kh + 8 * q + 2 * jp;
                    float e0, e1;
                    if (fwd) {
                        e0 = 0.25f * __expf(trans[(krow + 0) * NN + nsg]);
                        e1 = 0.25f * __expf(trans[(krow + 1) * NN + nsg]);
                    } else {
                        e0 = 0.25f * __expf(trans[nsg * NN + krow + 0]);
                        e1 = 0.25f * __expf(trans[nsg * NN + krow + 1]);
                    }
                    af.u[jp] = __builtin_bit_cast(int, __builtin_amdgcn_cvt_pkrtz(e0, e1));
                }
                Af[g][kh] = af.h;
            }
        }

        // Initial u: F col 0 = exp(alpha0 - m0) at lane's 16 states, else 1.
        if (fwd) {
            const float* p0 = emit + (size_t)b * NN;   // emit[0][b][*]
            m0loc = p0[0] + strans[0];
            const f32x4 e0 = *(const f32x4*)(p0 + 8 * q);
            const f32x4 e1 = *(const f32x4*)(p0 + 8 * q + 4);
            const f32x4 e2 = *(const f32x4*)(p0 + 32 + 8 * q);
            const f32x4 e3 = *(const f32x4*)(p0 + 32 + 8 * q + 4);
            const f32x4 s0 = *(const f32x4*)(strans + 8 * q);
            const f32x4 s1 = *(const f32x4*)(strans + 8 * q + 4);
            const f32x4 s2 = *(const f32x4*)(strans + 32 + 8 * q);
            const f32x4 s3 = *(const f32x4*)(strans + 32 + 8 * q + 4);
            #pragma unroll
            for (int j = 0; j < 4; ++j) {
                uLo[j]     = (m15 == 0) ? __expf(e0[j] + s0[j] - m0loc) : 1.f;
                uLo[4 + j] = (m15 == 0) ? __expf(e1[j] + s1[j] - m0loc) : 1.f;
                uHi[j]     = (m15 == 0) ? __expf(e2[j] + s2[j] - m0loc) : 1.f;
                uHi[4 + j] = (m15 == 0) ? __expf(e3[j] + s3[j] - m0loc) : 1.f;
            }
        } else {
            #pragma unroll
            for (int j = 0; j < 8; ++j) { uLo[j] = 1.f; uHi[j] = 1.f; }
        }

        // Initial per-column scale: d from the column-group max (xor16/32 mixes
        // exactly lanes {c, c+16, c+32, c+48}).
        float mx = uLo[0];
        #pragma unroll
        for (int j = 1; j < 8; ++j) mx = fmaxf(mx, uLo[j]);
        #pragma unroll
        for (int j = 0; j < 8; ++j) mx = fmaxf(mx, uHi[j]);
        mx = fmaxf(mx, __shfl_xor(mx, 16, 64));
        mx = fmaxf(mx, __shfl_xor(mx, 32, 64));
        int   d  = (int)((__float_as_uint(mx) >> 23) & 0xff) - 127 + 4;
        float sD = __int_as_float((127 - d) << 23);
        int   e_acc = 0;

        // Initial pack (F chains feed B-fragments directly; B packs in-step).
        AFrag BF0, BF1;
        #pragma unroll
        for (int r = 0; r < 4; ++r) {
            BF0.u[r] = __builtin_bit_cast(int, __builtin_amdgcn_cvt_pkrtz(uLo[2 * r], uLo[2 * r + 1]));
            BF1.u[r] = __builtin_bit_cast(int, __builtin_amdgcn_cvt_pkrtz(uHi[2 * r], uHi[2 * r + 1]));
        }

        float sLo[8], sHi[8];
        int   eSnap = 0;
        #pragma unroll
        for (int j = 0; j < 8; ++j) { sLo[j] = uLo[j]; sHi[j] = uHi[j]; }

        auto rowOf = [&](int j) -> int {
            int r = fwd ? (t0 + j) : (tLq - j);
            r = r < 0 ? 0 : (r > TT - 1 ? TT - 1 : r);
            return r;
        };
        auto LDW = [&](int j, f32x4& r0, f32x4& r1, f32x4& r2, f32x4& r3) {
            const int rr = rowOf(j);
            const float* p = emit + ((size_t)rr * BB + b) * NN;
            r0 = *(const f32x4*)(p + 8 * q);
            r1 = *(const f32x4*)(p + 8 * q + 4);
            r2 = *(const f32x4*)(p + 32 + 8 * q);
            r3 = *(const f32x4*)(p + 32 + 8 * q + 4);
        };
        auto SNAP = [&]() {
            #pragma unroll
            for (int j = 0; j < 8; ++j) { sLo[j] = uLo[j]; sHi[j] = uHi[j]; }
            eSnap = e_acc;
        };

        auto STEP = [&](f32x4& r0, f32x4& r1, f32x4& r2, f32x4& r3, int jn) {
            // w·2^-d for this step (sD from the previous step's probe)
            float wt0[8], wt1[8];
            #pragma unroll
            for (int jj = 0; jj < 4; ++jj) {
                wt0[jj]     = __expf(r0[jj]) * sD;
                wt0[4 + jj] = __expf(r1[jj]) * sD;
                wt1[jj]     = __expf(r2[jj]) * sD;
                wt1[4 + jj] = __expf(r3[jj]) * sD;
            }
            LDW(jn, r0, r1, r2, r3);   // prefetch 4 steps ahead

            int pf;
            if (fwd) {
                const f32x4 aA0 = __builtin_amdgcn_mfma_f32_16x16x32_f16(Af[0][0], BF0.h, zero4, 0, 0, 0);
                const f32x4 aA1 = __builtin_amdgcn_mfma_f32_16x16x32_f16(Af[1][0], BF0.h, zero4, 0, 0, 0);
                const f32x4 aA2 = __builtin_amdgcn_mfma_f32_16x16x32_f16(Af[2][0], BF0.h, zero4, 0, 0, 0);
                const f32x4 aA3 = __builtin_amdgcn_mfma_f32_16x16x32_f16(Af[3][0], BF0.h, zero4, 0, 0, 0);
                const f32x4 ac0 = __builtin_amdgcn_mfma_f32_16x16x32_f16(Af[0][1], BF1.h, aA0, 0, 0, 0);
                const f32x4 ac1 = __builtin_amdgcn_mfma_f32_16x16x32_f16(Af[1][1], BF1.h, aA1, 0, 0, 0);
                const f32x4 ac2 = __builtin_amdgcn_mfma_f32_16x16x32_f16(Af[2][1], BF1.h, aA2, 0, 0, 0);
                const f32x4 ac3 = __builtin_amdgcn_mfma_f32_16x16x32_f16(Af[3][1], BF1.h, aA3, 0, 0, 0);
                pf = __builtin_amdgcn_ds_bpermute(m15 << 2, __builtin_bit_cast(int, ac0[0]));
                #pragma unroll
                for (int r = 0; r < 4; ++r) {
                    uLo[2 * r]     = ac0[r] * wt0[2 * r];
                    uLo[2 * r + 1] = ac1[r] * wt0[2 * r + 1];
                    uHi[2 * r]     = ac2[r] * wt1[2 * r];
                    uHi[2 * r + 1] = ac3[r] * wt1[2 * r + 1];
                }
                #pragma unroll
                for (int r = 0; r < 4; ++r) {
                    BF0.u[r] = __builtin_bit_cast(int, __builtin_amdgcn_cvt_pkrtz(uLo[2 * r], uLo[2 * r + 1]));
                    BF1.u[r] = __builtin_bit_cast(int, __builtin_amdgcn_cvt_pkrtz(uHi[2 * r], uHi[2 * r + 1]));
                }
            } else {
                // bwd: v' = E (w ⊙ v)
                float v0[8], v1[8];
                #pragma unroll
                for (int j = 0; j < 8; ++j) { v0[j] = uLo[j] * wt0[j]; v1[j] = uHi[j] * wt1[j]; }
                #pragma unroll
                for (int r = 0; r < 4; ++r) {
                    BF0.u[r] = __builtin_bit_cast(int, __builtin_amdgcn_cvt_pkrtz(v0[2 * r], v0[2 * r + 1]));
                    BF1.u[r] = __builtin_bit_cast(int, __builtin_amdgcn_cvt_pkrtz(v1[2 * r], v1[2 * r + 1]));
                }
                const f32x4 aA0 = __builtin_amdgcn_mfma_f32_16x16x32_f16(Af[0][0], BF0.h, zero4, 0, 0, 0);
                const f32x4 aA1 = __builtin_amdgcn_mfma_f32_16x16x32_f16(Af[1][0], BF0.h, zero4, 0, 0, 0);
                const f32x4 aA2 = __builtin_amdgcn_mfma_f32_16x16x32_f16(Af[2][0], BF0.h, zero4, 0, 0, 0);
                const f32x4 aA3 = __builtin_amdgcn_mfma_f32_16x16x32_f16(Af[3][0], BF0.h, zero4, 0, 0, 0);
                const f32x4 ac0 = __builtin_amdgcn_mfma_f32_16x16x32_f16(Af[0][1], BF1.h, aA0, 0, 0, 0);
                const f32x4 ac1 = __builtin_amdgcn_mfma_f32_16x16x32_f16(Af[1][1], BF1.h, aA1, 0, 0, 0);
                const f32x4 ac2 = __builtin_amdgcn_mfma_f32_16x16x32_f16(Af[2][1], BF1.h, aA2, 0, 0, 0);
                const f32x4 ac3 = __builtin_amdgcn_mfma_f32_16x16x32_f16(Af[3][1], BF1.h, aA3, 0, 0, 0);
                pf = __builtin_amdgcn_ds_bpermute(m15 << 2, __builtin_bit_cast(int, ac0[0]));
                #pragma unroll
                for (int r = 0; r < 4; ++r) {
                    uLo[2 * r]     = ac0[r];
                    uLo[2 * r + 1] = ac1[r];
                    uHi[2 * r]     = ac2[r];
                    uHi[2 * r + 1] = ac3[r];
                }
            }
            e_acc += d + 2;   // +2 restores the 0.25=2^-2 folded into A (exact)
            d  = ((pf >> 23) & 0xff) - 127 + 4;
            sD = __int_as_float((127 - d) << 23);
        };

        // main loop: prefetch depth 4 via named buffer rotation
        f32x4 a0, a1, a2, a3, b0, b1, b2, b3;
        f32x4 c0, c1, c2, c3, d0, d1, d2, d3;
        LDW(0, a0, a1, a2, a3);
        LDW(1, b0, b1, b2, b3);
        LDW(2, c0, c1, c2, c3);
        LDW(3, d0, d1, d2, d3);
        #pragma unroll 1
        for (int i = 0; i < SCH; i += 4) {
            if (i     == sB) SNAP();
            STEP(a0, a1, a2, a3, min(i + 4, SCH - 1));
            if (i + 1 == sB) SNAP();
            STEP(b0, b1, b2, b3, min(i + 5, SCH - 1));
            if (i + 2 == sB) SNAP();
            STEP(c0, c1, c2, c3, min(i + 6, SCH - 1));
            if (i + 3 == sB) SNAP();
            STEP(d0, d1, d2, d3, min(i + 7, SCH - 1));
        }
        if (sB == SCH) SNAP();

        // store results (only columns 0..7; duplicates skipped)
        if (m15 < 8) {
            const bool us = (m15 == Bc);
            float* dst = fwd ? &FL[m15][0] : &RL[m15][0];
            f32x4 w0, w1, w2, w3;
            #pragma unroll
            for (int j = 0; j < 4; ++j) {
                w0[j] = us ? sLo[j]     : uLo[j];
                w1[j] = us ? sLo[4 + j] : uLo[4 + j];
                w2[j] = us ? sHi[j]     : uHi[j];
                w3[j] = us ? sHi[4 + j] : uHi[4 + j];
            }
            *(f32x4*)(dst + 8 * q)          = w0;
            *(f32x4*)(dst + 8 * q + 4)      = w1;
            *(f32x4*)(dst + 32 + 8 * q)     = w2;
            *(f32x4*)(dst + 32 + 8 * q + 4) = w3;
            if (q == 0) (fwd ? esF : esB)[m15] = us ? eSnap : e_acc;
        }
    } else {
        // ---- wave 2: fused gold score (overlaps the chains) ----
        int tvals[TT / 64];
        #pragma unroll
        for (int i = 0; i < TT / 64; ++i)
            tvals[i] = target[(size_t)(64 * i + k) * BB + b];

        float g = 0.f;
        int prev_last = 0;
        #pragma unroll
        for (int i = 0; i < TT / 64; ++i) {
            const int tt = 64 * i + k;
            const int tgt = tvals[i];
            int tprev = __shfl_up(tvals[i], 1, 64);
            if (k == 0) tprev = prev_last;                       // carry across i
            prev_last = __builtin_amdgcn_readlane(tvals[i], 63);
            if (tt < len) {
                float v = emit[((size_t)tt * BB + b) * NN + tgt];
                v += (tt == 0) ? strans[tgt] : trans[tprev * NN + tgt];
                if (tt == len - 1) v += etrans[tgt];
                g += v;
            }
        }
        g = wave_sum(g);
        if (k == 0) atomicAdd(out, -g);
    }

    __syncthreads();

    // ---- combine + optional exact replay + epilogue: wave 0 ----
    if (wv == 0) {
        float x    = FL[0][k];
        float Ltot = LN2F * (float)esF[0];
        const int Cend = exact ? (Bc - 1) : Bc;

        // rank-1: M_c x = F_c (R_c^T x)/(1^T F_c); chunk scales via esB.
        for (int c = 1; c <= Cend; ++c) {
            const float num = wave_sum(RL[c][k] * x);
            const float den = wave_sum(FL[c][k]);
            Ltot += __logf(num / den) + LN2F * (float)esB[c];
            x = FL[c][k];
        }

        if (exact) {
            // replay the short boundary chunk exactly (replicated columns;
            // wave-uniform d via readfirstlane = col0/state0, r12 scheme),
            // now with a 1-row software pipeline on the emit loads.
            xbuf[k] = x;
            asm volatile("" ::: "memory");
            float vLo[8], vHi[8];
            #pragma unroll
            for (int j = 0; j < 8; ++j) {
                vLo[j] = xbuf[8 * q + j];
                vHi[j] = xbuf[32 + 8 * q + j];
            }
            AFrag B0, B1;
            #pragma unroll
            for (int r = 0; r < 4; ++r) {
                B0.u[r] = __builtin_bit_cast(int, __builtin_amdgcn_cvt_pkrtz(vLo[2 * r], vLo[2 * r + 1]));
                B1.u[r] = __builtin_bit_cast(int, __builtin_amdgcn_cvt_pkrtz(vHi[2 * r], vHi[2 * r + 1]));
            }
            int eR = 0;
            const int t0B = 1 + SCH * Bc;
            f32x4 r0, r1, r2, r3;
            {
                const float* p = emit + ((size_t)t0B * BB + b) * NN;
                r0 = *(const f32x4*)(p + 8 * q);
                r1 = *(const f32x4*)(p + 8 * q + 4);
                r2 = *(const f32x4*)(p + 32 + 8 * q);
                r3 = *(const f32x4*)(p + 32 + 8 * q + 4);
            }
            #pragma unroll 1
            for (int j = 0; j < sB; ++j) {
                float wt0[8], wt1[8];
                #pragma unroll
                for (int jj = 0; jj < 4; ++jj) {
                    wt0[jj]     = __expf(r0[jj]);
                    wt0[4 + jj] = __expf(r1[jj]);
                    wt1[jj]     = __expf(r2[jj]);
                    wt1[4 + jj] = __expf(r3[jj]);
                }
                {   // prefetch next row (clamped; last iteration's load unused)
                    const int rn = (t0B + j + 1 < TT) ? (t0B + j + 1) : (TT - 1);
                    const float* p = emit + ((size_t)rn * BB + b) * NN;
                    r0 = *(const f32x4*)(p + 8 * q);
                    r1 = *(const f32x4*)(p + 8 * q + 4);
                    r2 = *(const f32x4*)(p + 32 + 8 * q);
                    r3 = *(const f32x4*)(p + 32 + 8 * q + 4);
                }
                const f32x4 aA0 = __builtin_amdgcn_mfma_f32_16x16x32_f16(Af[0][0], B0.h, zero4, 0, 0, 0);
                const f32x4 aA1 = __builtin_amdgcn_mfma_f32_16x16x32_f16(Af[1][0], B0.h, zero4, 0, 0, 0);
                const f32x4 aA2 = __builtin_amdgcn_mfma_f32_16x16x32_f16(Af[2][0], B0.h, zero4, 0, 0, 0);
                const f32x4 aA3 = __builtin_amdgcn_mfma_f32_16x16x32_f16(Af[3][0], B0.h, zero4, 0, 0, 0);
                const f32x4 ac0 = __builtin_amdgcn_mfma_f32_16x16x32_f16(Af[0][1], B1.h, aA0, 0, 0, 0);
                const f32x4 ac1 = __builtin_amdgcn_mfma_f32_16x16x32_f16(Af[1][1], B1.h, aA1, 0, 0, 0);
                const f32x4 ac2 = __builtin_amdgcn_mfma_f32_16x16x32_f16(Af[2][1], B1.h, aA2, 0, 0, 0);
                const f32x4 ac3 = __builtin_amdgcn_mfma_f32_16x16x32_f16(Af[3][1], B1.h, aA3, 0, 0, 0);
                const int e = (int)((__builtin_amdgcn_readfirstlane(__float_as_uint(ac0[0])) >> 23) & 0xff) - 127 + 4;
                const float sE = __int_as_float((127 - e) << 23);
                #pragma unroll
                for (int r = 0; r < 4; ++r) {
                    vLo[2 * r]     = ac0[r] * wt0[2 * r]     * sE;
                    vLo[2 * r + 1] = ac1[r] * wt0[2 * r + 1] * sE;
                    vHi[2 * r]     = ac2[r] * wt1[2 * r]     * sE;
                    vHi[2 * r + 1] = ac3[r] * wt1[2 * r + 1] * sE;
                }
                #pragma unroll
                for (int r = 0; r < 4; ++r) {
                    B0.u[r] = __builtin_bit_cast(int, __builtin_amdgcn_cvt_pkrtz(vLo[2 * r], vLo[2 * r + 1]));
                    B1.u[r] = __builtin_bit_cast(int, __builtin_amdgcn_cvt_pkrtz(vHi[2 * r], vHi[2 * r + 1]));
                }
                eR += e + 2;
            }
            // write back (all columns identical; duplicate writes benign)
            asm volatile("" ::: "memory");
            *(f32x4*)&xbuf[8 * q]          = *(f32x4*)&vLo[0];
            *(f32x4*)&xbuf[8 * q + 4]      = *(f32x4*)&vLo[4];
            *(f32x4*)&xbuf[32 + 8 * q]     = *(f32x4*)&vHi[0];
            *(f32x4*)&xbuf[32 + 8 * q + 4] = *(f32x4*)&vHi[4];
            asm volatile("" ::: "memory");
            x = xbuf[k];
            Ltot += LN2F * (float)eR;
        }

        // logZ_b = m0 + Ltot + logsumexp_k(log(x_k) + etrans[k])
        const float la = __logf(x) + etrans[k];   // x==0 -> -inf -> exp -> 0: fine
        const float m2 = wave_max(la);
        const float sm = wave_sum(__expf(la - m2));
        const float logZ_b = m0loc + Ltot + m2 + __logf(sm);

        if (k == 0) atomicAdd(out, logZ_b);
    }
}

extern "C" void kernel_launch(void* const* d_in, const int* in_sizes, int n_in,
                              void* d_out, int out_size, void* d_ws, size_t ws_size,
                              hipStream_t stream) {
    const float* emit   = (const float*)d_in[0];
    const float* trans  = (const float*)d_in[1];
    const float* strans = (const float*)d_in[2];
    const float* etrans = (const float*)d_in[3];
    const int*   target = (const int*)d_in[4];
    const void*  mask   = d_in[5];
    float* out = (float*)d_out;

    hipLaunchKernelGGL(zero_kernel, dim3(1), dim3(64), 0, stream, out);
    hipLaunchKernelGGL(crf_fwd_kernel, dim3(BB), dim3(192), 0, stream,
                       emit, trans, strans, etrans, target, mask, out);
}